// Round 9
// baseline (104034.473 us; speedup 1.0000x reference)
//
#include <hip/hip_runtime.h>
#include <hip/hip_bf16.h>

#define N_LAYERS 1000
#define DD 100
#define DOUT 10
#define TM 64
#define ROWB 264                  // act row stride bytes: 66 words = 2 mod 32 -> 2-way banks (free)
#define PLANE (TM * ROWB)         // 16896 B per plane (H or L)
#define SMEM_BYTES (2 * PLANE)    // 33792 B -> 4 wgs/CU (LDS-capped at 16 waves/CU)
#define LCHUNK 14336              // packed W bytes per (layer, group) per split
#define LSTRIDE (2 * LCHUNK)      // 28672 B per layer per split
#define POFF_MAX ((size_t)(N_LAYERS - 1) * LSTRIDE + 6 * 2048)   // last valid fragment offset

typedef short s4v __attribute__((ext_vector_type(4)));
typedef short s8v __attribute__((ext_vector_type(8)));
typedef float f16v __attribute__((ext_vector_type(16)));

__device__ __forceinline__ unsigned short f2bf(float f) {
  __hip_bfloat16 h = __float2bfloat16(f);   // HW RNE
  return *reinterpret_cast<unsigned short*>(&h);
}
__device__ __forceinline__ float bf2f(unsigned short h) {
  return __uint_as_float(((unsigned)h) << 16);
}

// ---------------- prologue: W (f32) + bias -> lane-packed bf16 hi/lo fragments ----------------
// byte off = (L*2+g)*LCHUNK + ks*2048 + f*1024 + lane*16
// frag: n = g*64+f*32+(lane&31), k = ks*16+(lane>>5)*8+j ; k==100 holds bias; pads zero.
__global__ __launch_bounds__(256)
void presplit_kernel(const float* __restrict__ W, const float* __restrict__ b,
                     char* __restrict__ hi_g, char* __restrict__ lo_g) {
  int idx = blockIdx.x * 256 + threadIdx.x;
  if (idx >= N_LAYERS * 2 * 7 * 2 * 64) return;
  int lane = idx & 63;
  int f = (idx >> 6) & 1;
  int r = idx >> 7;
  int ks = r % 7;
  int q = r / 7;
  int g = q & 1;
  int L = q >> 1;
  int n = g * 64 + f * 32 + (lane & 31);
  int k0 = ks * 16 + (lane >> 5) * 8;
  s8v hv, lv;
#pragma unroll
  for (int j = 0; j < 8; ++j) {
    int k = k0 + j;
    float v = 0.0f;
    if (n < DD) {
      if (k < DD) v = W[((size_t)L * DD + n) * DD + k];
      else if (k == DD) v = b[(size_t)L * DD + n];
    }
    unsigned short h = f2bf(v);
    float rr = v - bf2f(h);
    hv[j] = (short)h;
    lv[j] = (short)f2bf(rr);
  }
  *(s8v*)(hi_g + (size_t)idx * 16) = hv;
  *(s8v*)(lo_g + (size_t)idx * 16) = lv;
}

// fallback W gather from raw f32 (used only when d_ws is too small)
__device__ __forceinline__ void wload_f32(s8v* h, s8v* l, int L, int ks, int g,
                                          int l31, int lhi,
                                          const float* __restrict__ W_g,
                                          const float* __restrict__ b_g) {
  int k0 = ks * 16 + lhi * 8;
#pragma unroll
  for (int f = 0; f < 2; ++f) {
    int n = g * 64 + f * 32 + l31;
    s8v hv, lv;
#pragma unroll
    for (int j = 0; j < 8; ++j) {
      int k = k0 + j;
      float v = 0.0f;
      if (n < DD) {
        if (k < DD) v = W_g[((size_t)L * DD + n) * DD + k];
        else if (k == DD) v = b_g[(size_t)L * DD + n];
      }
      unsigned short hh = f2bf(v);
      float rr = v - bf2f(hh);
      hv[j] = (short)hh;
      lv[j] = (short)f2bf(rr);
    }
    h[f] = hv;
    l[f] = lv;
  }
}

// ---------------- one layer, phase P of 4 (static W-slot indices, depth-4 pipeline) ---------
// Global fragment stream t = 7L+ks lives in slot t&3. Preload t=0..3; at step t consume
// slot t&3 = (3P+ks)&3 (L === P mod 4, since 7 === 3 mod 4), then refill it with fragment
// t+4. poff = byte offset of fragment t+4: within a layer +2048; across the layer boundary
// (kn==6 -> next kn==0) delta = LSTRIDE - 6*2048 = 16384.  [r8 bug: advanced 28672]
template <int PRE, int P>
__device__ __forceinline__ void layer_step(
    int L, const char* __restrict__ rb, char* __restrict__ wb,
    int g, int l31, int lhi,
    const char* __restrict__ pH, const char* __restrict__ pL, size_t& poff,
    s8v (&wh)[4][2], s8v (&wl)[4][2], f16v (&xr)[2], const f16v& zro,
    const float* __restrict__ W_g, const float* __restrict__ b_g) {
  f16v acc[2];
#pragma unroll
  for (int ks = 0; ks < 7; ++ks) {
    const int s = (3 * P + ks) & 3;
    s4v a0 = *(const s4v*)(rb + ks * 32);
    s4v a1 = *(const s4v*)(rb + ks * 32 + 8);
    s4v c0 = *(const s4v*)(rb + PLANE + ks * 32);
    s4v c1 = *(const s4v*)(rb + PLANE + ks * 32 + 8);
    s8v ah = __builtin_shufflevector(a0, a1, 0, 1, 2, 3, 4, 5, 6, 7);
    s8v al = __builtin_shufflevector(c0, c1, 0, 1, 2, 3, 4, 5, 6, 7);
    if (ks == 0) {
      acc[0] = __builtin_amdgcn_mfma_f32_32x32x16_bf16(wh[s][0], ah, zro, 0, 0, 0);
      acc[1] = __builtin_amdgcn_mfma_f32_32x32x16_bf16(wh[s][1], ah, zro, 0, 0, 0);
    } else {
      acc[0] = __builtin_amdgcn_mfma_f32_32x32x16_bf16(wh[s][0], ah, acc[0], 0, 0, 0);
      acc[1] = __builtin_amdgcn_mfma_f32_32x32x16_bf16(wh[s][1], ah, acc[1], 0, 0, 0);
    }
    acc[0] = __builtin_amdgcn_mfma_f32_32x32x16_bf16(wh[s][0], al, acc[0], 0, 0, 0);
    acc[1] = __builtin_amdgcn_mfma_f32_32x32x16_bf16(wh[s][1], al, acc[1], 0, 0, 0);
    acc[0] = __builtin_amdgcn_mfma_f32_32x32x16_bf16(wl[s][0], ah, acc[0], 0, 0, 0);
    acc[1] = __builtin_amdgcn_mfma_f32_32x32x16_bf16(wl[s][1], ah, acc[1], 0, 0, 0);

    // refill the slot just consumed with fragment t+4
    const int nks = (ks + 4) % 7;     // static: kn of the fragment being loaded
    if (PRE) {
      if (poff <= POFF_MAX) {
        wh[s][0] = *(const s8v*)(pH + poff);
        wh[s][1] = *(const s8v*)(pH + poff + 1024);
        wl[s][0] = *(const s8v*)(pL + poff);
        wl[s][1] = *(const s8v*)(pL + poff + 1024);
      }
      poff += (nks == 6) ? (LSTRIDE - 6 * 2048) : 2048;   // wrap delta = 16384
    } else {
      const int Ln = L + (ks >= 3 ? 1 : 0);
      if (Ln < N_LAYERS) wload_f32(wh[s], wl[s], Ln, nks, g, l31, lhi, W_g, b_g);
    }
  }

  __syncthreads();   // all act reads of layer L complete

  // ---- epilogue: relu (+residual at block end), split hi/lo, in-place write ----
  const bool bend = ((L % 10) == 9);
#pragma unroll
  for (int f = 0; f < 2; ++f) {
#pragma unroll
    for (int q = 0; q < 4; ++q) {
      const int n0 = g * 64 + f * 32 + 8 * q + 4 * lhi;
      char* dst = wb + f * 64 + q * 16;
      if (n0 == 100) {   // bias column: act[100]=1.0, pads 101..103 = 0
        s4v hq, lq;
        hq[0] = (short)0x3F80; hq[1] = 0; hq[2] = 0; hq[3] = 0;
        lq[0] = 0; lq[1] = 0; lq[2] = 0; lq[3] = 0;
        *(s4v*)dst = hq;
        *(s4v*)(dst + PLANE) = lq;
      } else {
        s4v hq, lq;
#pragma unroll
        for (int j = 0; j < 4; ++j) {
          const int r = q * 4 + j;
          float o = fmaxf(acc[f][r], 0.0f);
          if (bend) { o += xr[f][r]; xr[f][r] = o; }
          unsigned short h = f2bf(o);
          float rr = o - bf2f(h);
          hq[j] = (short)h;
          lq[j] = (short)f2bf(rr);
        }
        *(s4v*)dst = hq;
        *(s4v*)(dst + PLANE) = lq;
      }
    }
  }
  __syncthreads();   // writes visible before next layer's reads
}

// ---------------- main kernel: 1024 wgs x 256 thr, 4 wgs/CU, single resident round ----------
// wg = 64 batch rows, 4 waves. wave wv: mi = wv&1 (rows mi*32+l31), g = wv>>1 (channels
// [g*64, g*64+64)). Padded act layout (all LDS ops base-reg + immediate), depth-4 W pipeline.
template <int PRE>
__global__ __launch_bounds__(256, 4)
void resnet_main(const float* __restrict__ x_g,
                 const float* __restrict__ W_g, const float* __restrict__ b_g,
                 const float* __restrict__ Wf_g, const float* __restrict__ bf_g,
                 float* __restrict__ out_g,
                 const char* __restrict__ whi_g, const char* __restrict__ wlo_g) {
  extern __shared__ char smem[];

  const int tid = threadIdx.x;
  const int lane = tid & 63;
  const int wv = tid >> 6;
  const int mi = wv & 1;
  const int g = wv >> 1;
  const int l31 = lane & 31;
  const int lhi = lane >> 5;
  const size_t mbase = (size_t)blockIdx.x * TM;
  const int arow = mi * 32 + l31;

  // ---- initial activation staging: split(x); k==100 -> 1.0 (bias col); k>100 -> 0 ----
  for (int idx = tid; idx < TM * 16; idx += 256) {
    int m = idx >> 4, kb = idx & 15;
    s4v h0, h1, l0, l1;
#pragma unroll
    for (int j = 0; j < 8; ++j) {
      int k = kb * 8 + j;
      float v = (k < DD) ? x_g[(mbase + m) * DD + k] : (k == DD ? 1.0f : 0.0f);
      unsigned short hh = f2bf(v);
      float rr = v - bf2f(hh);
      unsigned short ll = f2bf(rr);
      if (j < 4) { h0[j] = (short)hh; l0[j] = (short)ll; }
      else       { h1[j - 4] = (short)hh; l1[j - 4] = (short)ll; }
    }
    char* p = smem + m * ROWB + kb * 16;
    *(s4v*)p = h0;
    *(s4v*)(p + 8) = h1;
    *(s4v*)(p + PLANE) = l0;
    *(s4v*)(p + PLANE + 8) = l1;
  }

  // ---- residual: block input in registers, C-fragment layout of this wave's 2 n-tiles ----
  f16v xr[2];
#pragma unroll
  for (int f = 0; f < 2; ++f)
#pragma unroll
    for (int r = 0; r < 16; ++r) {
      int n = g * 64 + f * 32 + (r & 3) + 8 * (r >> 2) + 4 * lhi;
      xr[f][r] = (n < DD) ? x_g[(mbase + arow) * DD + n] : 0.0f;
    }

  f16v zro;
#pragma unroll
  for (int r = 0; r < 16; ++r) zro[r] = 0.0f;

  // ---- depth-4 W register pipeline: preload fragments t=0..3 (layer 0, ks 0..3) ----
  const char* pH = whi_g + g * LCHUNK + lane * 16;
  const char* pL = wlo_g + g * LCHUNK + lane * 16;
  s8v wh[4][2], wl[4][2];
  if (PRE) {
#pragma unroll
    for (int s = 0; s < 4; ++s) {
      wh[s][0] = *(const s8v*)(pH + s * 2048);
      wh[s][1] = *(const s8v*)(pH + s * 2048 + 1024);
      wl[s][0] = *(const s8v*)(pL + s * 2048);
      wl[s][1] = *(const s8v*)(pL + s * 2048 + 1024);
    }
  } else {
#pragma unroll
    for (int s = 0; s < 4; ++s) wload_f32(wh[s], wl[s], 0, s, g, l31, lhi, W_g, b_g);
  }
  size_t poff = 4 * 2048;   // next fragment to load: t=4 (layer 0, ks 4)

  __syncthreads();

  // all LDS accesses: these two base registers + compile-time immediates
  const char* rb = smem + arow * ROWB + lhi * 16;              // act reads
  char* wb = smem + arow * ROWB + g * 128 + lhi * 8;           // act writes

  for (int L = 0; L < N_LAYERS; L += 4) {
    layer_step<PRE, 0>(L + 0, rb, wb, g, l31, lhi, pH, pL, poff, wh, wl, xr, zro, W_g, b_g);
    layer_step<PRE, 1>(L + 1, rb, wb, g, l31, lhi, pH, pL, poff, wh, wl, xr, zro, W_g, b_g);
    layer_step<PRE, 2>(L + 2, rb, wb, g, l31, lhi, pH, pL, poff, wh, wl, xr, zro, W_g, b_g);
    layer_step<PRE, 3>(L + 3, rb, wb, g, l31, lhi, pH, pL, poff, wh, wl, xr, zro, W_g, b_g);
  }

  // ---- final projection: out = act @ Wf^T + bf ----
  if (tid < TM) {
    int m = tid;
    const char* p = smem + m * ROWB;
    float xv[104];
#pragma unroll
    for (int kb = 0; kb < 13; ++kb) {
      s4v h0 = *(const s4v*)(p + kb * 16);
      s4v h1 = *(const s4v*)(p + kb * 16 + 8);
      s4v l0 = *(const s4v*)(p + PLANE + kb * 16);
      s4v l1 = *(const s4v*)(p + PLANE + kb * 16 + 8);
#pragma unroll
      for (int j = 0; j < 4; ++j) {
        xv[kb * 8 + j]     = bf2f((unsigned short)h0[j]) + bf2f((unsigned short)l0[j]);
        xv[kb * 8 + 4 + j] = bf2f((unsigned short)h1[j]) + bf2f((unsigned short)l1[j]);
      }
    }
#pragma unroll
    for (int o = 0; o < DOUT; ++o) {
      float s = bf_g[o];
#pragma unroll
      for (int k = 0; k < DD; ++k) s += xv[k] * Wf_g[o * DD + k];
      out_g[(mbase + m) * DOUT + o] = s;
    }
  }
}

extern "C" void kernel_launch(void* const* d_in, const int* in_sizes, int n_in,
                              void* d_out, int out_size, void* d_ws, size_t ws_size,
                              hipStream_t stream) {
  const float* x = (const float*)d_in[0];
  const float* W = (const float*)d_in[1];
  const float* b = (const float*)d_in[2];
  const float* Wf = (const float*)d_in[3];
  const float* bf = (const float*)d_in[4];
  float* out = (float*)d_out;

  const size_t split_bytes = (size_t)N_LAYERS * 2 * LCHUNK;   // 28.672 MB per split
  const size_t need = 2 * split_bytes;                        // 57.344 MB
  const int nwg = 65536 / TM;                                 // 1024
  if (ws_size >= need) {
    char* whi = (char*)d_ws;
    char* wlo = whi + split_bytes;
    const int chunks = N_LAYERS * 2 * 7 * 2 * 64;             // 1,792,000
    presplit_kernel<<<(chunks + 255) / 256, 256, 0, stream>>>(W, b, whi, wlo);
    (void)hipFuncSetAttribute(reinterpret_cast<const void*>(resnet_main<1>),
                              hipFuncAttributeMaxDynamicSharedMemorySize, SMEM_BYTES);
    resnet_main<1><<<nwg, 256, SMEM_BYTES, stream>>>(x, W, b, Wf, bf, out, whi, wlo);
  } else {
    (void)hipFuncSetAttribute(reinterpret_cast<const void*>(resnet_main<0>),
                              hipFuncAttributeMaxDynamicSharedMemorySize, SMEM_BYTES);
    resnet_main<0><<<nwg, 256, SMEM_BYTES, stream>>>(x, W, b, Wf, bf, out, nullptr, nullptr);
  }
}

// Round 10
// 4698.668 us; speedup vs baseline: 22.1413x; 22.1413x over previous
//
#include <hip/hip_runtime.h>
#include <hip/hip_bf16.h>

#define N_LAYERS 1000
#define DD 100
#define DOUT 10
#define TM 64
#define ROWB 264                  // act row stride bytes: 66 words = 2 mod 32 -> 2-way banks (free)
#define PLANE (TM * ROWB)         // 16896 B = one act buffer (single bf16 plane)
#define SMEM_BYTES (2 * PLANE)    // double-buffered: 33792 B -> 4 wgs/CU
#define LCHUNK 14336              // packed W bytes per (layer, group) per split
#define LSTRIDE (2 * LCHUNK)      // 28672 B per layer per split

typedef short s4v __attribute__((ext_vector_type(4)));
typedef short s8v __attribute__((ext_vector_type(8)));
typedef float f16v __attribute__((ext_vector_type(16)));

__device__ __forceinline__ unsigned short f2bf(float f) {
  __hip_bfloat16 h = __float2bfloat16(f);   // HW RNE
  return *reinterpret_cast<unsigned short*>(&h);
}
__device__ __forceinline__ float bf2f(unsigned short h) {
  return __uint_as_float(((unsigned)h) << 16);
}

// ---------------- prologue: W (f32) + bias -> lane-packed bf16 hi/lo fragments ----------------
// byte off = (L*2+g)*LCHUNK + ks*2048 + f*1024 + lane*16
// frag: n = g*64+f*32+(lane&31), k = ks*16+(lane>>5)*8+j ; k==100 holds bias; pads zero.
__global__ __launch_bounds__(256)
void presplit_kernel(const float* __restrict__ W, const float* __restrict__ b,
                     char* __restrict__ hi_g, char* __restrict__ lo_g) {
  int idx = blockIdx.x * 256 + threadIdx.x;
  if (idx >= N_LAYERS * 2 * 7 * 2 * 64) return;
  int lane = idx & 63;
  int f = (idx >> 6) & 1;
  int r = idx >> 7;
  int ks = r % 7;
  int q = r / 7;
  int g = q & 1;
  int L = q >> 1;
  int n = g * 64 + f * 32 + (lane & 31);
  int k0 = ks * 16 + (lane >> 5) * 8;
  s8v hv, lv;
#pragma unroll
  for (int j = 0; j < 8; ++j) {
    int k = k0 + j;
    float v = 0.0f;
    if (n < DD) {
      if (k < DD) v = W[((size_t)L * DD + n) * DD + k];
      else if (k == DD) v = b[(size_t)L * DD + n];
    }
    unsigned short h = f2bf(v);
    float rr = v - bf2f(h);
    hv[j] = (short)h;
    lv[j] = (short)f2bf(rr);
  }
  *(s8v*)(hi_g + (size_t)idx * 16) = hv;
  *(s8v*)(lo_g + (size_t)idx * 16) = lv;
}

// fallback W gather from raw f32 (used only when d_ws is too small)
__device__ __forceinline__ void wload_f32(s8v* h, s8v* l, int L, int ks, int g,
                                          int l31, int lhi,
                                          const float* __restrict__ W_g,
                                          const float* __restrict__ b_g) {
  int k0 = ks * 16 + lhi * 8;
#pragma unroll
  for (int f = 0; f < 2; ++f) {
    int n = g * 64 + f * 32 + l31;
    s8v hv, lv;
#pragma unroll
    for (int j = 0; j < 8; ++j) {
      int k = k0 + j;
      float v = 0.0f;
      if (n < DD) {
        if (k < DD) v = W_g[((size_t)L * DD + n) * DD + k];
        else if (k == DD) v = b_g[(size_t)L * DD + n];
      }
      unsigned short hh = f2bf(v);
      float rr = v - bf2f(hh);
      hv[j] = (short)hh;
      lv[j] = (short)f2bf(rr);
    }
    h[f] = hv;
    l[f] = lv;
  }
}

// packed W fragment load (depth-2 slots, r7-proven)
template <int PRE>
__device__ __forceinline__ void wload(s8v* h, s8v* l,
                                      const char* __restrict__ pH, const char* __restrict__ pL,
                                      int off, int L, int ks, int g, int l31, int lhi,
                                      const float* __restrict__ W_g,
                                      const float* __restrict__ b_g) {
  if (PRE) {
    h[0] = *(const s8v*)(pH + off);
    h[1] = *(const s8v*)(pH + off + 1024);
    l[0] = *(const s8v*)(pL + off);
    l[1] = *(const s8v*)(pL + off + 1024);
  } else {
    wload_f32(h, l, L, ks, g, l31, lhi, W_g, b_g);
  }
}

// ---------------- one layer: read act (bf16) from RB, write next act to WB ----------------
// 2-product numerics: z = (Wh + Wl) @ a_bf16.  One barrier at layer end (double buffer).
template <int PRE>
__device__ __forceinline__ void do_layer(
    int L, const char* __restrict__ rb, char* __restrict__ wb,
    int g, int l31, int lhi,
    const char* __restrict__ pH, const char* __restrict__ pL, int woff,
    s8v (&wh)[2][2], s8v (&wl)[2][2], f16v (&xr)[2],
    const float* __restrict__ W_g, const float* __restrict__ b_g) {
  f16v acc[2];
#pragma unroll
  for (int f = 0; f < 2; ++f)
#pragma unroll
    for (int r = 0; r < 16; ++r) acc[f][r] = 0.0f;

#pragma unroll
  for (int ks = 0; ks < 7; ++ks) {
    const int s = ks & 1;
    s4v a0 = *(const s4v*)(rb + ks * 32);
    s4v a1 = *(const s4v*)(rb + ks * 32 + 8);
    s8v ah = __builtin_shufflevector(a0, a1, 0, 1, 2, 3, 4, 5, 6, 7);
    acc[0] = __builtin_amdgcn_mfma_f32_32x32x16_bf16(wh[s][0], ah, acc[0], 0, 0, 0);
    acc[1] = __builtin_amdgcn_mfma_f32_32x32x16_bf16(wh[s][1], ah, acc[1], 0, 0, 0);
    acc[0] = __builtin_amdgcn_mfma_f32_32x32x16_bf16(wl[s][0], ah, acc[0], 0, 0, 0);
    acc[1] = __builtin_amdgcn_mfma_f32_32x32x16_bf16(wl[s][1], ah, acc[1], 0, 0, 0);

    // depth-2 prefetch; cross-layer refill at ks==6 (r7-proven schedule)
    if (ks < 5) {
      wload<PRE>(wh[s], wl[s], pH, pL, woff + (ks + 2) * 2048, L, ks + 2, g, l31, lhi, W_g, b_g);
    } else if (ks == 6 && L + 1 < N_LAYERS) {
      wload<PRE>(wh[0], wl[0], pH, pL, woff + LSTRIDE,        L + 1, 0, g, l31, lhi, W_g, b_g);
      wload<PRE>(wh[1], wl[1], pH, pL, woff + LSTRIDE + 2048, L + 1, 1, g, l31, lhi, W_g, b_g);
    }
  }

  // ---- epilogue: relu (+residual at block end), cast bf16, write to NEXT buffer ----
  const bool bend = ((L % 10) == 9);
#pragma unroll
  for (int f = 0; f < 2; ++f) {
#pragma unroll
    for (int q = 0; q < 4; ++q) {
      const int n0 = g * 64 + f * 32 + 8 * q + 4 * lhi;
      char* dst = wb + f * 64 + q * 16;
      if (n0 == 100) {   // bias column: act[100]=1.0, pads 101..103 = 0
        s4v hq;
        hq[0] = (short)0x3F80; hq[1] = 0; hq[2] = 0; hq[3] = 0;
        *(s4v*)dst = hq;
      } else {
        s4v hq;
#pragma unroll
        for (int j = 0; j < 4; ++j) {
          const int r = q * 4 + j;
          float o = fmaxf(acc[f][r], 0.0f);
          if (bend) { o += xr[f][r]; xr[f][r] = o; }   // stream stays exact in f32 regs
          hq[j] = (short)f2bf(o);
        }
        *(s4v*)dst = hq;
      }
    }
  }
  __syncthreads();   // single barrier: separates this layer's R/W from the next layer's
}

// ---------------- main kernel: 1024 wgs x 256 thr, 4 wgs/CU, single resident round ----------
// wg = 64 batch rows, 4 waves. wave wv: mi = wv&1 (rows mi*32+l31), g = wv>>1 (channels
// [g*64, g*64+64)). Single-bf16 act, double-buffered; W hi/lo split in regs (2 products).
template <int PRE>
__global__ __launch_bounds__(256, 4)
void resnet_main(const float* __restrict__ x_g,
                 const float* __restrict__ W_g, const float* __restrict__ b_g,
                 const float* __restrict__ Wf_g, const float* __restrict__ bf_g,
                 float* __restrict__ out_g,
                 const char* __restrict__ whi_g, const char* __restrict__ wlo_g) {
  extern __shared__ char smem[];

  const int tid = threadIdx.x;
  const int lane = tid & 63;
  const int wv = tid >> 6;
  const int mi = wv & 1;
  const int g = wv >> 1;
  const int l31 = lane & 31;
  const int lhi = lane >> 5;
  const size_t mbase = (size_t)blockIdx.x * TM;
  const int arow = mi * 32 + l31;

  // ---- initial activation staging into buf A: bf16(x); k==100 -> 1.0; k>100 -> 0 ----
  for (int idx = tid; idx < TM * 16; idx += 256) {
    int m = idx >> 4, kb = idx & 15;
    s4v h0, h1;
#pragma unroll
    for (int j = 0; j < 8; ++j) {
      int k = kb * 8 + j;
      float v = (k < DD) ? x_g[(mbase + m) * DD + k] : (k == DD ? 1.0f : 0.0f);
      if (j < 4) h0[j] = (short)f2bf(v);
      else       h1[j - 4] = (short)f2bf(v);
    }
    char* p = smem + m * ROWB + kb * 16;
    *(s4v*)p = h0;
    *(s4v*)(p + 8) = h1;
  }

  // ---- residual: block input in f32 registers, C-fragment layout (exact stream carrier) ----
  f16v xr[2];
#pragma unroll
  for (int f = 0; f < 2; ++f)
#pragma unroll
    for (int r = 0; r < 16; ++r) {
      int n = g * 64 + f * 32 + (r & 3) + 8 * (r >> 2) + 4 * lhi;
      xr[f][r] = (n < DD) ? x_g[(mbase + arow) * DD + n] : 0.0f;
    }

  // ---- W depth-2 register pipeline: preload ks=0,1 of layer 0 ----
  const char* pH = whi_g + g * LCHUNK + lane * 16;
  const char* pL = wlo_g + g * LCHUNK + lane * 16;
  s8v wh[2][2], wl[2][2];
  wload<PRE>(wh[0], wl[0], pH, pL, 0,    0, 0, g, l31, lhi, W_g, b_g);
  wload<PRE>(wh[1], wl[1], pH, pL, 2048, 0, 1, g, l31, lhi, W_g, b_g);

  __syncthreads();

  // buffer A = smem, buffer B = smem + PLANE; layer L reads buf[L&1], writes buf[~L&1]
  const char* rbA = smem + arow * ROWB + lhi * 16;
  const char* rbB = rbA + PLANE;
  char* wbA = smem + arow * ROWB + g * 128 + lhi * 8;
  char* wbB = wbA + PLANE;

  int woff = 0;
  for (int L = 0; L < N_LAYERS; L += 2) {
    do_layer<PRE>(L,     rbA, wbB, g, l31, lhi, pH, pL, woff,           wh, wl, xr, W_g, b_g);
    do_layer<PRE>(L + 1, rbB, wbA, g, l31, lhi, pH, pL, woff + LSTRIDE, wh, wl, xr, W_g, b_g);
    woff += 2 * LSTRIDE;
  }

  // ---- final projection: out = act @ Wf^T + bf  (act = buf A after layer 999) ----
  if (tid < TM) {
    int m = tid;
    const char* p = smem + m * ROWB;
    float xv[104];
#pragma unroll
    for (int kb = 0; kb < 13; ++kb) {
      s4v h0 = *(const s4v*)(p + kb * 16);
      s4v h1 = *(const s4v*)(p + kb * 16 + 8);
#pragma unroll
      for (int j = 0; j < 4; ++j) {
        xv[kb * 8 + j]     = bf2f((unsigned short)h0[j]);
        xv[kb * 8 + 4 + j] = bf2f((unsigned short)h1[j]);
      }
    }
#pragma unroll
    for (int o = 0; o < DOUT; ++o) {
      float s = bf_g[o];
#pragma unroll
      for (int k = 0; k < DD; ++k) s += xv[k] * Wf_g[o * DD + k];
      out_g[(mbase + m) * DOUT + o] = s;
    }
  }
}

extern "C" void kernel_launch(void* const* d_in, const int* in_sizes, int n_in,
                              void* d_out, int out_size, void* d_ws, size_t ws_size,
                              hipStream_t stream) {
  const float* x = (const float*)d_in[0];
  const float* W = (const float*)d_in[1];
  const float* b = (const float*)d_in[2];
  const float* Wf = (const float*)d_in[3];
  const float* bf = (const float*)d_in[4];
  float* out = (float*)d_out;

  const size_t split_bytes = (size_t)N_LAYERS * 2 * LCHUNK;   // 28.672 MB per split
  const size_t need = 2 * split_bytes;                        // 57.344 MB
  const int nwg = 65536 / TM;                                 // 1024
  if (ws_size >= need) {
    char* whi = (char*)d_ws;
    char* wlo = whi + split_bytes;
    const int chunks = N_LAYERS * 2 * 7 * 2 * 64;             // 1,792,000
    presplit_kernel<<<(chunks + 255) / 256, 256, 0, stream>>>(W, b, whi, wlo);
    (void)hipFuncSetAttribute(reinterpret_cast<const void*>(resnet_main<1>),
                              hipFuncAttributeMaxDynamicSharedMemorySize, SMEM_BYTES);
    resnet_main<1><<<nwg, 256, SMEM_BYTES, stream>>>(x, W, b, Wf, bf, out, whi, wlo);
  } else {
    (void)hipFuncSetAttribute(reinterpret_cast<const void*>(resnet_main<0>),
                              hipFuncAttributeMaxDynamicSharedMemorySize, SMEM_BYTES);
    resnet_main<0><<<nwg, 256, SMEM_BYTES, stream>>>(x, W, b, Wf, bf, out, nullptr, nullptr);
  }
}

// Round 11
// 3362.370 us; speedup vs baseline: 30.9408x; 1.3974x over previous
//
#include <hip/hip_runtime.h>
#include <hip/hip_bf16.h>

#define N_LAYERS 1000
#define DD 100
#define DOUT 10
#define TM 64
#define ROWB 264                  // act row stride bytes: 66 words = 2 mod 32 -> 2-way banks (free)
#define PLANE (TM * ROWB)         // 16896 B = one act buffer (single bf16 plane)
#define SMEM_BYTES (2 * PLANE)    // double-buffered: 33792 B -> 4 wgs/CU
#define ROW32 (32 * ROWB)         // 8448: +1 m-tile offset, compile-time immediate
#define LCHUNK 14336              // packed W bytes per (layer, group) per split
#define LSTRIDE (2 * LCHUNK)      // 28672 B per layer per split

typedef short s4v __attribute__((ext_vector_type(4)));
typedef short s8v __attribute__((ext_vector_type(8)));
typedef float f16v __attribute__((ext_vector_type(16)));

__device__ __forceinline__ unsigned short f2bf(float f) {
  __hip_bfloat16 h = __float2bfloat16(f);   // HW RNE
  return *reinterpret_cast<unsigned short*>(&h);
}
__device__ __forceinline__ float bf2f(unsigned short h) {
  return __uint_as_float(((unsigned)h) << 16);
}

// ---------------- prologue: W (f32) + bias -> lane-packed bf16 hi/lo fragments ----------------
// byte off = (L*2+g)*LCHUNK + ks*2048 + f*1024 + lane*16
// frag: n = g*64+f*32+(lane&31), k = ks*16+(lane>>5)*8+j ; k==100 holds bias; pads zero.
__global__ __launch_bounds__(256)
void presplit_kernel(const float* __restrict__ W, const float* __restrict__ b,
                     char* __restrict__ hi_g, char* __restrict__ lo_g) {
  int idx = blockIdx.x * 256 + threadIdx.x;
  if (idx >= N_LAYERS * 2 * 7 * 2 * 64) return;
  int lane = idx & 63;
  int f = (idx >> 6) & 1;
  int r = idx >> 7;
  int ks = r % 7;
  int q = r / 7;
  int g = q & 1;
  int L = q >> 1;
  int n = g * 64 + f * 32 + (lane & 31);
  int k0 = ks * 16 + (lane >> 5) * 8;
  s8v hv, lv;
#pragma unroll
  for (int j = 0; j < 8; ++j) {
    int k = k0 + j;
    float v = 0.0f;
    if (n < DD) {
      if (k < DD) v = W[((size_t)L * DD + n) * DD + k];
      else if (k == DD) v = b[(size_t)L * DD + n];
    }
    unsigned short h = f2bf(v);
    float rr = v - bf2f(h);
    hv[j] = (short)h;
    lv[j] = (short)f2bf(rr);
  }
  *(s8v*)(hi_g + (size_t)idx * 16) = hv;
  *(s8v*)(lo_g + (size_t)idx * 16) = lv;
}

// fallback W gather from raw f32 (used only when d_ws is too small)
__device__ __forceinline__ void wload_f32(s8v* h, s8v* l, int L, int ks, int g,
                                          int l31, int lhi,
                                          const float* __restrict__ W_g,
                                          const float* __restrict__ b_g) {
  int k0 = ks * 16 + lhi * 8;
#pragma unroll
  for (int f = 0; f < 2; ++f) {
    int n = g * 64 + f * 32 + l31;
    s8v hv, lv;
#pragma unroll
    for (int j = 0; j < 8; ++j) {
      int k = k0 + j;
      float v = 0.0f;
      if (n < DD) {
        if (k < DD) v = W_g[((size_t)L * DD + n) * DD + k];
        else if (k == DD) v = b_g[(size_t)L * DD + n];
      }
      unsigned short hh = f2bf(v);
      float rr = v - bf2f(hh);
      hv[j] = (short)hh;
      lv[j] = (short)f2bf(rr);
    }
    h[f] = hv;
    l[f] = lv;
  }
}

// packed W fragment load (depth-2 slots)
template <int PRE>
__device__ __forceinline__ void wload(s8v* h, s8v* l,
                                      const char* __restrict__ pH, const char* __restrict__ pL,
                                      int off, int L, int ks, int g, int l31, int lhi,
                                      const float* __restrict__ W_g,
                                      const float* __restrict__ b_g) {
  if (PRE) {
    h[0] = *(const s8v*)(pH + off);
    h[1] = *(const s8v*)(pH + off + 1024);
    l[0] = *(const s8v*)(pL + off);
    l[1] = *(const s8v*)(pL + off + 1024);
  } else {
    wload_f32(h, l, L, ks, g, l31, lhi, W_g, b_g);
  }
}

// ---------------- one layer: read act (bf16) from RB (2 m-tiles), write next act to WB -------
// Wave owns 64 rows x 64 channels: acc[mi][f]. One barrier per layer (double buffer).
template <int PRE>
__device__ __forceinline__ void do_layer(
    int L, const char* __restrict__ rb, char* __restrict__ wb,
    int g, int l31, int lhi,
    const char* __restrict__ pH, const char* __restrict__ pL, int woff,
    s8v (&wh)[2][2], s8v (&wl)[2][2], f16v (&xr)[2][2],
    const float* __restrict__ W_g, const float* __restrict__ b_g) {
  f16v acc[2][2];
#pragma unroll
  for (int mi = 0; mi < 2; ++mi)
#pragma unroll
    for (int f = 0; f < 2; ++f)
#pragma unroll
      for (int r = 0; r < 16; ++r) acc[mi][f][r] = 0.0f;

#pragma unroll
  for (int ks = 0; ks < 7; ++ks) {
    const int s = ks & 1;
    s4v a0 = *(const s4v*)(rb + ks * 32);
    s4v a1 = *(const s4v*)(rb + ks * 32 + 8);
    s4v b0 = *(const s4v*)(rb + ROW32 + ks * 32);
    s4v b1 = *(const s4v*)(rb + ROW32 + ks * 32 + 8);
    s8v ah0 = __builtin_shufflevector(a0, a1, 0, 1, 2, 3, 4, 5, 6, 7);
    s8v ah1 = __builtin_shufflevector(b0, b1, 0, 1, 2, 3, 4, 5, 6, 7);
    acc[0][0] = __builtin_amdgcn_mfma_f32_32x32x16_bf16(wh[s][0], ah0, acc[0][0], 0, 0, 0);
    acc[0][1] = __builtin_amdgcn_mfma_f32_32x32x16_bf16(wh[s][1], ah0, acc[0][1], 0, 0, 0);
    acc[1][0] = __builtin_amdgcn_mfma_f32_32x32x16_bf16(wh[s][0], ah1, acc[1][0], 0, 0, 0);
    acc[1][1] = __builtin_amdgcn_mfma_f32_32x32x16_bf16(wh[s][1], ah1, acc[1][1], 0, 0, 0);
    acc[0][0] = __builtin_amdgcn_mfma_f32_32x32x16_bf16(wl[s][0], ah0, acc[0][0], 0, 0, 0);
    acc[0][1] = __builtin_amdgcn_mfma_f32_32x32x16_bf16(wl[s][1], ah0, acc[0][1], 0, 0, 0);
    acc[1][0] = __builtin_amdgcn_mfma_f32_32x32x16_bf16(wl[s][0], ah1, acc[1][0], 0, 0, 0);
    acc[1][1] = __builtin_amdgcn_mfma_f32_32x32x16_bf16(wl[s][1], ah1, acc[1][1], 0, 0, 0);

    // depth-2 prefetch; cross-layer refill at ks==6 (r7-proven schedule)
    if (ks < 5) {
      wload<PRE>(wh[s], wl[s], pH, pL, woff + (ks + 2) * 2048, L, ks + 2, g, l31, lhi, W_g, b_g);
    } else if (ks == 6 && L + 1 < N_LAYERS) {
      wload<PRE>(wh[0], wl[0], pH, pL, woff + LSTRIDE,        L + 1, 0, g, l31, lhi, W_g, b_g);
      wload<PRE>(wh[1], wl[1], pH, pL, woff + LSTRIDE + 2048, L + 1, 1, g, l31, lhi, W_g, b_g);
    }
  }

  // ---- epilogue: relu (+residual at block end), cast bf16, write both m-tiles to WB ----
  const bool bend = ((L % 10) == 9);
#pragma unroll
  for (int mi = 0; mi < 2; ++mi) {
    char* dstm = wb + mi * ROW32;
#pragma unroll
    for (int f = 0; f < 2; ++f) {
#pragma unroll
      for (int q = 0; q < 4; ++q) {
        const int n0 = g * 64 + f * 32 + 8 * q + 4 * lhi;
        char* dst = dstm + f * 64 + q * 16;
        if (n0 == 100) {   // bias column: act[100]=1.0, pads 101..103 = 0
          s4v hq;
          hq[0] = (short)0x3F80; hq[1] = 0; hq[2] = 0; hq[3] = 0;
          *(s4v*)dst = hq;
        } else {
          s4v hq;
#pragma unroll
          for (int j = 0; j < 4; ++j) {
            const int r = q * 4 + j;
            float o = fmaxf(acc[mi][f][r], 0.0f);
            if (bend) { o += xr[mi][f][r]; xr[mi][f][r] = o; }   // exact f32 stream carrier
            hq[j] = (short)f2bf(o);
          }
          *(s4v*)dst = hq;
        }
      }
    }
  }
  __syncthreads();   // single barrier: separates this layer's R/W from the next layer's
}

// ---------------- main kernel: 1024 wgs x 128 thr, 4 wgs/CU ------------------------------
// wg = 64 batch rows, 2 waves. Wave wv = g owns channels [g*64, g*64+64) x ALL 64 rows
// (2 m-tiles) -> zero W duplication in the wg, W VMEM per CU halves vs r10.
template <int PRE>
__global__ __launch_bounds__(128, 2)
void resnet_main(const float* __restrict__ x_g,
                 const float* __restrict__ W_g, const float* __restrict__ b_g,
                 const float* __restrict__ Wf_g, const float* __restrict__ bf_g,
                 float* __restrict__ out_g,
                 const char* __restrict__ whi_g, const char* __restrict__ wlo_g) {
  extern __shared__ char smem[];

  const int tid = threadIdx.x;
  const int lane = tid & 63;
  const int g = tid >> 6;          // wave index == channel group
  const int l31 = lane & 31;
  const int lhi = lane >> 5;
  const size_t mbase = (size_t)blockIdx.x * TM;

  // ---- initial activation staging into buf A: bf16(x); k==100 -> 1.0; k>100 -> 0 ----
  for (int idx = tid; idx < TM * 16; idx += 128) {
    int m = idx >> 4, kb = idx & 15;
    s4v h0, h1;
#pragma unroll
    for (int j = 0; j < 8; ++j) {
      int k = kb * 8 + j;
      float v = (k < DD) ? x_g[(mbase + m) * DD + k] : (k == DD ? 1.0f : 0.0f);
      if (j < 4) h0[j] = (short)f2bf(v);
      else       h1[j - 4] = (short)f2bf(v);
    }
    char* p = smem + m * ROWB + kb * 16;
    *(s4v*)p = h0;
    *(s4v*)(p + 8) = h1;
  }

  // ---- residual: block input in f32 registers, C-fragment layout (2 m-tiles x 2 f) ----
  f16v xr[2][2];
#pragma unroll
  for (int mi = 0; mi < 2; ++mi)
#pragma unroll
    for (int f = 0; f < 2; ++f)
#pragma unroll
      for (int r = 0; r < 16; ++r) {
        int n = g * 64 + f * 32 + (r & 3) + 8 * (r >> 2) + 4 * lhi;
        xr[mi][f][r] = (n < DD) ? x_g[(mbase + mi * 32 + l31) * DD + n] : 0.0f;
      }

  // ---- W depth-2 register pipeline: preload ks=0,1 of layer 0 ----
  const char* pH = whi_g + g * LCHUNK + lane * 16;
  const char* pL = wlo_g + g * LCHUNK + lane * 16;
  s8v wh[2][2], wl[2][2];
  wload<PRE>(wh[0], wl[0], pH, pL, 0,    0, 0, g, l31, lhi, W_g, b_g);
  wload<PRE>(wh[1], wl[1], pH, pL, 2048, 0, 1, g, l31, lhi, W_g, b_g);

  __syncthreads();

  // buffer A = smem, buffer B = smem + PLANE; layer L reads buf[L&1], writes buf[~L&1]
  const char* rbA = smem + l31 * ROWB + lhi * 16;
  const char* rbB = rbA + PLANE;
  char* wbA = smem + l31 * ROWB + g * 128 + lhi * 8;
  char* wbB = wbA + PLANE;

  int woff = 0;
  for (int L = 0; L < N_LAYERS; L += 2) {
    do_layer<PRE>(L,     rbA, wbB, g, l31, lhi, pH, pL, woff,           wh, wl, xr, W_g, b_g);
    do_layer<PRE>(L + 1, rbB, wbA, g, l31, lhi, pH, pL, woff + LSTRIDE, wh, wl, xr, W_g, b_g);
    woff += 2 * LSTRIDE;
  }

  // ---- final projection: out = act @ Wf^T + bf  (act = buf A after layer 999) ----
  if (tid < TM) {
    int m = tid;
    const char* p = smem + m * ROWB;
    float xv[104];
#pragma unroll
    for (int kb = 0; kb < 13; ++kb) {
      s4v h0 = *(const s4v*)(p + kb * 16);
      s4v h1 = *(const s4v*)(p + kb * 16 + 8);
#pragma unroll
      for (int j = 0; j < 4; ++j) {
        xv[kb * 8 + j]     = bf2f((unsigned short)h0[j]);
        xv[kb * 8 + 4 + j] = bf2f((unsigned short)h1[j]);
      }
    }
#pragma unroll
    for (int o = 0; o < DOUT; ++o) {
      float s = bf_g[o];
#pragma unroll
      for (int k = 0; k < DD; ++k) s += xv[k] * Wf_g[o * DD + k];
      out_g[(mbase + m) * DOUT + o] = s;
    }
  }
}

extern "C" void kernel_launch(void* const* d_in, const int* in_sizes, int n_in,
                              void* d_out, int out_size, void* d_ws, size_t ws_size,
                              hipStream_t stream) {
  const float* x = (const float*)d_in[0];
  const float* W = (const float*)d_in[1];
  const float* b = (const float*)d_in[2];
  const float* Wf = (const float*)d_in[3];
  const float* bf = (const float*)d_in[4];
  float* out = (float*)d_out;

  const size_t split_bytes = (size_t)N_LAYERS * 2 * LCHUNK;   // 28.672 MB per split
  const size_t need = 2 * split_bytes;                        // 57.344 MB
  const int nwg = 65536 / TM;                                 // 1024
  if (ws_size >= need) {
    char* whi = (char*)d_ws;
    char* wlo = whi + split_bytes;
    const int chunks = N_LAYERS * 2 * 7 * 2 * 64;             // 1,792,000
    presplit_kernel<<<(chunks + 255) / 256, 256, 0, stream>>>(W, b, whi, wlo);
    (void)hipFuncSetAttribute(reinterpret_cast<const void*>(resnet_main<1>),
                              hipFuncAttributeMaxDynamicSharedMemorySize, SMEM_BYTES);
    resnet_main<1><<<nwg, 128, SMEM_BYTES, stream>>>(x, W, b, Wf, bf, out, whi, wlo);
  } else {
    (void)hipFuncSetAttribute(reinterpret_cast<const void*>(resnet_main<0>),
                              hipFuncAttributeMaxDynamicSharedMemorySize, SMEM_BYTES);
    resnet_main<0><<<nwg, 128, SMEM_BYTES, stream>>>(x, W, b, Wf, bf, out, nullptr, nullptr);
  }
}

// Round 12
// 2269.796 us; speedup vs baseline: 45.8343x; 1.4814x over previous
//
#include <hip/hip_runtime.h>
#include <hip/hip_bf16.h>

#define N_LAYERS 1000
#define DD 100
#define DOUT 10
#define TM 64
#define ROWB 264                  // act row stride bytes: 66 words = 2 mod 32 -> 2-way banks (free)
#define PLANE (TM * ROWB)         // 16896 B = one act buffer (single bf16 plane)
#define SMEM_BYTES (2 * PLANE)    // double-buffered: 33792 B -> 4 wgs/CU
#define ROW32 (32 * ROWB)         // 8448: +1 m-tile offset, compile-time immediate
#define LCHUNK 14336              // packed W bytes per (layer, group)
#define LSTRIDE (2 * LCHUNK)      // 28672 B per layer

typedef short s4v __attribute__((ext_vector_type(4)));
typedef short s8v __attribute__((ext_vector_type(8)));
typedef float f16v __attribute__((ext_vector_type(16)));

__device__ __forceinline__ unsigned short f2bf(float f) {
  __hip_bfloat16 h = __float2bfloat16(f);   // HW RNE
  return *reinterpret_cast<unsigned short*>(&h);
}
__device__ __forceinline__ float bf2f(unsigned short h) {
  return __uint_as_float(((unsigned)h) << 16);
}

// ---------------- prologue: W (f32) + bias -> lane-packed bf16 fragments (hi only) ----------
// byte off = (L*2+g)*LCHUNK + ks*2048 + f*1024 + lane*16
// frag: n = g*64+f*32+(lane&31), k = ks*16+(lane>>5)*8+j ; k==100 holds bias; pads zero.
__global__ __launch_bounds__(256)
void presplit_kernel(const float* __restrict__ W, const float* __restrict__ b,
                     char* __restrict__ hi_g) {
  int idx = blockIdx.x * 256 + threadIdx.x;
  if (idx >= N_LAYERS * 2 * 7 * 2 * 64) return;
  int lane = idx & 63;
  int f = (idx >> 6) & 1;
  int r = idx >> 7;
  int ks = r % 7;
  int q = r / 7;
  int g = q & 1;
  int L = q >> 1;
  int n = g * 64 + f * 32 + (lane & 31);
  int k0 = ks * 16 + (lane >> 5) * 8;
  s8v hv;
#pragma unroll
  for (int j = 0; j < 8; ++j) {
    int k = k0 + j;
    float v = 0.0f;
    if (n < DD) {
      if (k < DD) v = W[((size_t)L * DD + n) * DD + k];
      else if (k == DD) v = b[(size_t)L * DD + n];
    }
    hv[j] = (short)f2bf(v);
  }
  *(s8v*)(hi_g + (size_t)idx * 16) = hv;
}

// fallback W gather from raw f32 (used only when d_ws is too small)
__device__ __forceinline__ void wload_f32(s8v* h, int L, int ks, int g,
                                          int l31, int lhi,
                                          const float* __restrict__ W_g,
                                          const float* __restrict__ b_g) {
  int k0 = ks * 16 + lhi * 8;
#pragma unroll
  for (int f = 0; f < 2; ++f) {
    int n = g * 64 + f * 32 + l31;
    s8v hv;
#pragma unroll
    for (int j = 0; j < 8; ++j) {
      int k = k0 + j;
      float v = 0.0f;
      if (n < DD) {
        if (k < DD) v = W_g[((size_t)L * DD + n) * DD + k];
        else if (k == DD) v = b_g[(size_t)L * DD + n];
      }
      hv[j] = (short)f2bf(v);
    }
    h[f] = hv;
  }
}

// packed W fragment load (depth-2 slots)
template <int PRE>
__device__ __forceinline__ void wload(s8v* h, const char* __restrict__ pH,
                                      int off, int L, int ks, int g, int l31, int lhi,
                                      const float* __restrict__ W_g,
                                      const float* __restrict__ b_g) {
  if (PRE) {
    h[0] = *(const s8v*)(pH + off);
    h[1] = *(const s8v*)(pH + off + 1024);
  } else {
    wload_f32(h, L, ks, g, l31, lhi, W_g, b_g);
  }
}

// ---------------- one layer: read act (bf16) from RB (2 m-tiles), write next act to WB -------
// Single product z = Wh @ a. Wave owns 64 rows x 64 channels: acc[mi][f].
// One barrier per layer (double buffer).
template <int PRE>
__device__ __forceinline__ void do_layer(
    int L, const char* __restrict__ rb, char* __restrict__ wb,
    int g, int l31, int lhi,
    const char* __restrict__ pH, int woff,
    s8v (&wh)[2][2], f16v (&xr)[2][2],
    const float* __restrict__ W_g, const float* __restrict__ b_g) {
  f16v acc[2][2];
#pragma unroll
  for (int mi = 0; mi < 2; ++mi)
#pragma unroll
    for (int f = 0; f < 2; ++f)
#pragma unroll
      for (int r = 0; r < 16; ++r) acc[mi][f][r] = 0.0f;

#pragma unroll
  for (int ks = 0; ks < 7; ++ks) {
    const int s = ks & 1;
    s4v a0 = *(const s4v*)(rb + ks * 32);
    s4v a1 = *(const s4v*)(rb + ks * 32 + 8);
    s4v b0 = *(const s4v*)(rb + ROW32 + ks * 32);
    s4v b1 = *(const s4v*)(rb + ROW32 + ks * 32 + 8);
    s8v ah0 = __builtin_shufflevector(a0, a1, 0, 1, 2, 3, 4, 5, 6, 7);
    s8v ah1 = __builtin_shufflevector(b0, b1, 0, 1, 2, 3, 4, 5, 6, 7);
    acc[0][0] = __builtin_amdgcn_mfma_f32_32x32x16_bf16(wh[s][0], ah0, acc[0][0], 0, 0, 0);
    acc[0][1] = __builtin_amdgcn_mfma_f32_32x32x16_bf16(wh[s][1], ah0, acc[0][1], 0, 0, 0);
    acc[1][0] = __builtin_amdgcn_mfma_f32_32x32x16_bf16(wh[s][0], ah1, acc[1][0], 0, 0, 0);
    acc[1][1] = __builtin_amdgcn_mfma_f32_32x32x16_bf16(wh[s][1], ah1, acc[1][1], 0, 0, 0);

    // depth-2 prefetch; cross-layer refill at ks==6 (r7-proven schedule)
    if (ks < 5) {
      wload<PRE>(wh[s], pH, woff + (ks + 2) * 2048, L, ks + 2, g, l31, lhi, W_g, b_g);
    } else if (ks == 6 && L + 1 < N_LAYERS) {
      wload<PRE>(wh[0], pH, woff + LSTRIDE,        L + 1, 0, g, l31, lhi, W_g, b_g);
      wload<PRE>(wh[1], pH, woff + LSTRIDE + 2048, L + 1, 1, g, l31, lhi, W_g, b_g);
    }
  }

  // ---- epilogue: relu (+residual at block end), cast bf16, write both m-tiles to WB ----
  const bool bend = ((L % 10) == 9);
#pragma unroll
  for (int mi = 0; mi < 2; ++mi) {
    char* dstm = wb + mi * ROW32;
#pragma unroll
    for (int f = 0; f < 2; ++f) {
#pragma unroll
      for (int q = 0; q < 4; ++q) {
        const int n0 = g * 64 + f * 32 + 8 * q + 4 * lhi;
        char* dst = dstm + f * 64 + q * 16;
        if (n0 == 100) {   // bias column: act[100]=1.0, pads 101..103 = 0
          s4v hq;
          hq[0] = (short)0x3F80; hq[1] = 0; hq[2] = 0; hq[3] = 0;
          *(s4v*)dst = hq;
        } else {
          s4v hq;
#pragma unroll
          for (int j = 0; j < 4; ++j) {
            const int r = q * 4 + j;
            float o = fmaxf(acc[mi][f][r], 0.0f);
            if (bend) { o += xr[mi][f][r]; xr[mi][f][r] = o; }   // exact f32 stream carrier
            hq[j] = (short)f2bf(o);
          }
          *(s4v*)dst = hq;
        }
      }
    }
  }
  __syncthreads();   // single barrier: separates this layer's R/W from the next layer's
}

// ---------------- main kernel: 1024 wgs x 128 thr, 4 wgs/CU ------------------------------
// wg = 64 batch rows, 2 waves. Wave wv = g owns channels [g*64, g*64+64) x ALL 64 rows
// (2 m-tiles) -> zero W duplication in the wg.
template <int PRE>
__global__ __launch_bounds__(128, 2)
void resnet_main(const float* __restrict__ x_g,
                 const float* __restrict__ W_g, const float* __restrict__ b_g,
                 const float* __restrict__ Wf_g, const float* __restrict__ bf_g,
                 float* __restrict__ out_g,
                 const char* __restrict__ whi_g) {
  extern __shared__ char smem[];

  const int tid = threadIdx.x;
  const int lane = tid & 63;
  const int g = tid >> 6;          // wave index == channel group
  const int l31 = lane & 31;
  const int lhi = lane >> 5;
  const size_t mbase = (size_t)blockIdx.x * TM;

  // ---- initial activation staging into buf A: bf16(x); k==100 -> 1.0; k>100 -> 0 ----
  for (int idx = tid; idx < TM * 16; idx += 128) {
    int m = idx >> 4, kb = idx & 15;
    s4v h0, h1;
#pragma unroll
    for (int j = 0; j < 8; ++j) {
      int k = kb * 8 + j;
      float v = (k < DD) ? x_g[(mbase + m) * DD + k] : (k == DD ? 1.0f : 0.0f);
      if (j < 4) h0[j] = (short)f2bf(v);
      else       h1[j - 4] = (short)f2bf(v);
    }
    char* p = smem + m * ROWB + kb * 16;
    *(s4v*)p = h0;
    *(s4v*)(p + 8) = h1;
  }

  // ---- residual: block input in f32 registers, C-fragment layout (2 m-tiles x 2 f) ----
  f16v xr[2][2];
#pragma unroll
  for (int mi = 0; mi < 2; ++mi)
#pragma unroll
    for (int f = 0; f < 2; ++f)
#pragma unroll
      for (int r = 0; r < 16; ++r) {
        int n = g * 64 + f * 32 + (r & 3) + 8 * (r >> 2) + 4 * lhi;
        xr[mi][f][r] = (n < DD) ? x_g[(mbase + mi * 32 + l31) * DD + n] : 0.0f;
      }

  // ---- W depth-2 register pipeline: preload ks=0,1 of layer 0 ----
  const char* pH = whi_g + g * LCHUNK + lane * 16;
  s8v wh[2][2];
  wload<PRE>(wh[0], pH, 0,    0, 0, g, l31, lhi, W_g, b_g);
  wload<PRE>(wh[1], pH, 2048, 0, 1, g, l31, lhi, W_g, b_g);

  __syncthreads();

  // buffer A = smem, buffer B = smem + PLANE; layer L reads buf[L&1], writes buf[~L&1]
  const char* rbA = smem + l31 * ROWB + lhi * 16;
  const char* rbB = rbA + PLANE;
  char* wbA = smem + l31 * ROWB + g * 128 + lhi * 8;
  char* wbB = wbA + PLANE;

  int woff = 0;
  for (int L = 0; L < N_LAYERS; L += 2) {
    do_layer<PRE>(L,     rbA, wbB, g, l31, lhi, pH, woff,           wh, xr, W_g, b_g);
    do_layer<PRE>(L + 1, rbB, wbA, g, l31, lhi, pH, woff + LSTRIDE, wh, xr, W_g, b_g);
    woff += 2 * LSTRIDE;
  }

  // ---- final projection: out = act @ Wf^T + bf  (act = buf A after layer 999) ----
  if (tid < TM) {
    int m = tid;
    const char* p = smem + m * ROWB;
    float xv[104];
#pragma unroll
    for (int kb = 0; kb < 13; ++kb) {
      s4v h0 = *(const s4v*)(p + kb * 16);
      s4v h1 = *(const s4v*)(p + kb * 16 + 8);
#pragma unroll
      for (int j = 0; j < 4; ++j) {
        xv[kb * 8 + j]     = bf2f((unsigned short)h0[j]);
        xv[kb * 8 + 4 + j] = bf2f((unsigned short)h1[j]);
      }
    }
#pragma unroll
    for (int o = 0; o < DOUT; ++o) {
      float s = bf_g[o];
#pragma unroll
      for (int k = 0; k < DD; ++k) s += xv[k] * Wf_g[o * DD + k];
      out_g[(mbase + m) * DOUT + o] = s;
    }
  }
}

extern "C" void kernel_launch(void* const* d_in, const int* in_sizes, int n_in,
                              void* d_out, int out_size, void* d_ws, size_t ws_size,
                              hipStream_t stream) {
  const float* x = (const float*)d_in[0];
  const float* W = (const float*)d_in[1];
  const float* b = (const float*)d_in[2];
  const float* Wf = (const float*)d_in[3];
  const float* bf = (const float*)d_in[4];
  float* out = (float*)d_out;

  const size_t need = (size_t)N_LAYERS * 2 * LCHUNK;          // 28.672 MB (hi only)
  const int nwg = 65536 / TM;                                 // 1024
  if (ws_size >= need) {
    char* whi = (char*)d_ws;
    const int chunks = N_LAYERS * 2 * 7 * 2 * 64;             // 1,792,000
    presplit_kernel<<<(chunks + 255) / 256, 256, 0, stream>>>(W, b, whi);
    (void)hipFuncSetAttribute(reinterpret_cast<const void*>(resnet_main<1>),
                              hipFuncAttributeMaxDynamicSharedMemorySize, SMEM_BYTES);
    resnet_main<1><<<nwg, 128, SMEM_BYTES, stream>>>(x, W, b, Wf, bf, out, whi);
  } else {
    (void)hipFuncSetAttribute(reinterpret_cast<const void*>(resnet_main<0>),
                              hipFuncAttributeMaxDynamicSharedMemorySize, SMEM_BYTES);
    resnet_main<0><<<nwg, 128, SMEM_BYTES, stream>>>(x, W, b, Wf, bf, out, nullptr);
  }
}

// Round 13
// 2143.890 us; speedup vs baseline: 48.5260x; 1.0587x over previous
//
#include <hip/hip_runtime.h>
#include <hip/hip_bf16.h>

#define N_LAYERS 1000
#define DD 100
#define DOUT 10
#define TM 64
#define ROWB 264                  // act row stride bytes: 66 words = 2 mod 32 -> 2-way banks (free)
#define PLANE (TM * ROWB)         // 16896 B = one act buffer (single bf16 plane)
#define SMEM_BYTES (2 * PLANE)    // double-buffered: 33792 B -> 4 wgs/CU
#define ROW32 (32 * ROWB)         // 8448: +1 m-tile offset, compile-time immediate
#define LCHUNK 14336              // packed W bytes per (layer, group)
#define LSTRIDE (2 * LCHUNK)      // 28672 B per layer
#define POFF_MAX ((size_t)(N_LAYERS - 1) * LSTRIDE + 6 * 2048)   // last valid fragment offset

typedef short s4v __attribute__((ext_vector_type(4)));
typedef short s8v __attribute__((ext_vector_type(8)));
typedef float f16v __attribute__((ext_vector_type(16)));

__device__ __forceinline__ unsigned short f2bf(float f) {
  __hip_bfloat16 h = __float2bfloat16(f);   // HW RNE
  return *reinterpret_cast<unsigned short*>(&h);
}
__device__ __forceinline__ float bf2f(unsigned short h) {
  return __uint_as_float(((unsigned)h) << 16);
}

// ---------------- prologue: W (f32) + bias -> lane-packed bf16 fragments (hi only) ----------
// byte off = (L*2+g)*LCHUNK + ks*2048 + f*1024 + lane*16
// frag: n = g*64+f*32+(lane&31), k = ks*16+(lane>>5)*8+j ; k==100 holds bias; pads zero.
__global__ __launch_bounds__(256)
void presplit_kernel(const float* __restrict__ W, const float* __restrict__ b,
                     char* __restrict__ hi_g) {
  int idx = blockIdx.x * 256 + threadIdx.x;
  if (idx >= N_LAYERS * 2 * 7 * 2 * 64) return;
  int lane = idx & 63;
  int f = (idx >> 6) & 1;
  int r = idx >> 7;
  int ks = r % 7;
  int q = r / 7;
  int g = q & 1;
  int L = q >> 1;
  int n = g * 64 + f * 32 + (lane & 31);
  int k0 = ks * 16 + (lane >> 5) * 8;
  s8v hv;
#pragma unroll
  for (int j = 0; j < 8; ++j) {
    int k = k0 + j;
    float v = 0.0f;
    if (n < DD) {
      if (k < DD) v = W[((size_t)L * DD + n) * DD + k];
      else if (k == DD) v = b[(size_t)L * DD + n];
    }
    hv[j] = (short)f2bf(v);
  }
  *(s8v*)(hi_g + (size_t)idx * 16) = hv;
}

// fallback W gather from raw f32 (used only when d_ws is too small)
__device__ __forceinline__ void wload_f32(s8v* h, int L, int ks, int g,
                                          int l31, int lhi,
                                          const float* __restrict__ W_g,
                                          const float* __restrict__ b_g) {
  int k0 = ks * 16 + lhi * 8;
#pragma unroll
  for (int f = 0; f < 2; ++f) {
    int n = g * 64 + f * 32 + l31;
    s8v hv;
#pragma unroll
    for (int j = 0; j < 8; ++j) {
      int k = k0 + j;
      float v = 0.0f;
      if (n < DD) {
        if (k < DD) v = W_g[((size_t)L * DD + n) * DD + k];
        else if (k == DD) v = b_g[(size_t)L * DD + n];
      }
      hv[j] = (short)f2bf(v);
    }
    h[f] = hv;
  }
}

// ---------------- one layer, phase P of 4 (static W-slot indices, depth-4 pipeline) ---------
// Fragment stream t = 7L+ks lives in slot t&3. Preload t=0..3; at step t consume slot
// t&3 = (3P+ks)&3 (since L === P mod 4 and 7 === 3 mod 4), then refill it with fragment
// t+4. poff = byte offset of fragment t+4: within a layer +2048; across the boundary
// (nks==6 -> next kn==0) delta = LSTRIDE - 6*2048 = 16384 (r9-verified algebra).
template <int PRE, int P>
__device__ __forceinline__ void layer_step(
    int L, const char* __restrict__ rb, char* __restrict__ wb,
    int g, int l31, int lhi,
    const char* __restrict__ pH, size_t& poff,
    s8v (&wh)[4][2], f16v (&xr)[2][2], const f16v& zro,
    const float* __restrict__ W_g, const float* __restrict__ b_g) {
  f16v acc[2][2];
#pragma unroll
  for (int ks = 0; ks < 7; ++ks) {
    const int s = (3 * P + ks) & 3;
    s4v a0 = *(const s4v*)(rb + ks * 32);
    s4v a1 = *(const s4v*)(rb + ks * 32 + 8);
    s4v b0 = *(const s4v*)(rb + ROW32 + ks * 32);
    s4v b1 = *(const s4v*)(rb + ROW32 + ks * 32 + 8);
    s8v ah0 = __builtin_shufflevector(a0, a1, 0, 1, 2, 3, 4, 5, 6, 7);
    s8v ah1 = __builtin_shufflevector(b0, b1, 0, 1, 2, 3, 4, 5, 6, 7);
    if (ks == 0) {
      acc[0][0] = __builtin_amdgcn_mfma_f32_32x32x16_bf16(wh[s][0], ah0, zro, 0, 0, 0);
      acc[0][1] = __builtin_amdgcn_mfma_f32_32x32x16_bf16(wh[s][1], ah0, zro, 0, 0, 0);
      acc[1][0] = __builtin_amdgcn_mfma_f32_32x32x16_bf16(wh[s][0], ah1, zro, 0, 0, 0);
      acc[1][1] = __builtin_amdgcn_mfma_f32_32x32x16_bf16(wh[s][1], ah1, zro, 0, 0, 0);
    } else {
      acc[0][0] = __builtin_amdgcn_mfma_f32_32x32x16_bf16(wh[s][0], ah0, acc[0][0], 0, 0, 0);
      acc[0][1] = __builtin_amdgcn_mfma_f32_32x32x16_bf16(wh[s][1], ah0, acc[0][1], 0, 0, 0);
      acc[1][0] = __builtin_amdgcn_mfma_f32_32x32x16_bf16(wh[s][0], ah1, acc[1][0], 0, 0, 0);
      acc[1][1] = __builtin_amdgcn_mfma_f32_32x32x16_bf16(wh[s][1], ah1, acc[1][1], 0, 0, 0);
    }

    // refill the slot just consumed with fragment t+4
    const int nks = (ks + 4) % 7;     // static
    if (PRE) {
      if (poff <= POFF_MAX) {
        wh[s][0] = *(const s8v*)(pH + poff);
        wh[s][1] = *(const s8v*)(pH + poff + 1024);
      }
      poff += (nks == 6) ? (LSTRIDE - 6 * 2048) : 2048;   // wrap delta = 16384
    } else {
      const int Ln = L + (ks >= 3 ? 1 : 0);
      if (Ln < N_LAYERS) wload_f32(wh[s], Ln, nks, g, l31, lhi, W_g, b_g);
    }
  }

  // ---- epilogue: relu (+residual at block end), cast bf16, write both m-tiles to WB ----
  const bool bend = ((L % 10) == 9);
#pragma unroll
  for (int mi = 0; mi < 2; ++mi) {
    char* dstm = wb + mi * ROW32;
#pragma unroll
    for (int f = 0; f < 2; ++f) {
#pragma unroll
      for (int q = 0; q < 4; ++q) {
        const int n0 = g * 64 + f * 32 + 8 * q + 4 * lhi;
        char* dst = dstm + f * 64 + q * 16;
        if (n0 == 100) {   // bias column: act[100]=1.0, pads 101..103 = 0
          s4v hq;
          hq[0] = (short)0x3F80; hq[1] = 0; hq[2] = 0; hq[3] = 0;
          *(s4v*)dst = hq;
        } else {
          s4v hq;
#pragma unroll
          for (int j = 0; j < 4; ++j) {
            const int r = q * 4 + j;
            float o = fmaxf(acc[mi][f][r], 0.0f);
            if (bend) { o += xr[mi][f][r]; xr[mi][f][r] = o; }   // exact f32 stream carrier
            hq[j] = (short)f2bf(o);
          }
          *(s4v*)dst = hq;
        }
      }
    }
  }
  __syncthreads();   // single barrier: separates this layer's R/W from the next layer's
}

// ---------------- main kernel: 1024 wgs x 128 thr, 4 wgs/CU ------------------------------
// wg = 64 batch rows, 2 waves. Wave wv = g owns channels [g*64, g*64+64) x ALL 64 rows
// (2 m-tiles) -> zero W duplication in the wg. Depth-4 W register pipeline.
template <int PRE>
__global__ __launch_bounds__(128, 2)
void resnet_main(const float* __restrict__ x_g,
                 const float* __restrict__ W_g, const float* __restrict__ b_g,
                 const float* __restrict__ Wf_g, const float* __restrict__ bf_g,
                 float* __restrict__ out_g,
                 const char* __restrict__ whi_g) {
  extern __shared__ char smem[];

  const int tid = threadIdx.x;
  const int lane = tid & 63;
  const int g = tid >> 6;          // wave index == channel group
  const int l31 = lane & 31;
  const int lhi = lane >> 5;
  const size_t mbase = (size_t)blockIdx.x * TM;

  // ---- initial activation staging into buf A: bf16(x); k==100 -> 1.0; k>100 -> 0 ----
  for (int idx = tid; idx < TM * 16; idx += 128) {
    int m = idx >> 4, kb = idx & 15;
    s4v h0, h1;
#pragma unroll
    for (int j = 0; j < 8; ++j) {
      int k = kb * 8 + j;
      float v = (k < DD) ? x_g[(mbase + m) * DD + k] : (k == DD ? 1.0f : 0.0f);
      if (j < 4) h0[j] = (short)f2bf(v);
      else       h1[j - 4] = (short)f2bf(v);
    }
    char* p = smem + m * ROWB + kb * 16;
    *(s4v*)p = h0;
    *(s4v*)(p + 8) = h1;
  }

  // ---- residual: block input in f32 registers, C-fragment layout (2 m-tiles x 2 f) ----
  f16v xr[2][2];
#pragma unroll
  for (int mi = 0; mi < 2; ++mi)
#pragma unroll
    for (int f = 0; f < 2; ++f)
#pragma unroll
      for (int r = 0; r < 16; ++r) {
        int n = g * 64 + f * 32 + (r & 3) + 8 * (r >> 2) + 4 * lhi;
        xr[mi][f][r] = (n < DD) ? x_g[(mbase + mi * 32 + l31) * DD + n] : 0.0f;
      }

  f16v zro;
#pragma unroll
  for (int r = 0; r < 16; ++r) zro[r] = 0.0f;

  // ---- depth-4 W register pipeline: preload fragments t=0..3 (layer 0, ks 0..3) ----
  const char* pH = whi_g + g * LCHUNK + lane * 16;
  s8v wh[4][2];
  if (PRE) {
#pragma unroll
    for (int s = 0; s < 4; ++s) {
      wh[s][0] = *(const s8v*)(pH + s * 2048);
      wh[s][1] = *(const s8v*)(pH + s * 2048 + 1024);
    }
  } else {
#pragma unroll
    for (int s = 0; s < 4; ++s) wload_f32(wh[s], 0, s, g, l31, lhi, W_g, b_g);
  }
  size_t poff = 4 * 2048;   // next fragment to load: t=4 (layer 0, ks 4)

  __syncthreads();

  // buffer A = smem, buffer B = smem + PLANE; layer L reads buf[L&1], writes buf[~L&1]
  const char* rbA = smem + l31 * ROWB + lhi * 16;
  const char* rbB = rbA + PLANE;
  char* wbA = smem + l31 * ROWB + g * 128 + lhi * 8;
  char* wbB = wbA + PLANE;

  for (int L = 0; L < N_LAYERS; L += 4) {
    layer_step<PRE, 0>(L + 0, rbA, wbB, g, l31, lhi, pH, poff, wh, xr, zro, W_g, b_g);
    layer_step<PRE, 1>(L + 1, rbB, wbA, g, l31, lhi, pH, poff, wh, xr, zro, W_g, b_g);
    layer_step<PRE, 2>(L + 2, rbA, wbB, g, l31, lhi, pH, poff, wh, xr, zro, W_g, b_g);
    layer_step<PRE, 3>(L + 3, rbB, wbA, g, l31, lhi, pH, poff, wh, xr, zro, W_g, b_g);
  }

  // ---- final projection: out = act @ Wf^T + bf  (act = buf A after layer 999) ----
  if (tid < TM) {
    int m = tid;
    const char* p = smem + m * ROWB;
    float xv[104];
#pragma unroll
    for (int kb = 0; kb < 13; ++kb) {
      s4v h0 = *(const s4v*)(p + kb * 16);
      s4v h1 = *(const s4v*)(p + kb * 16 + 8);
#pragma unroll
      for (int j = 0; j < 4; ++j) {
        xv[kb * 8 + j]     = bf2f((unsigned short)h0[j]);
        xv[kb * 8 + 4 + j] = bf2f((unsigned short)h1[j]);
      }
    }
#pragma unroll
    for (int o = 0; o < DOUT; ++o) {
      float s = bf_g[o];
#pragma unroll
      for (int k = 0; k < DD; ++k) s += xv[k] * Wf_g[o * DD + k];
      out_g[(mbase + m) * DOUT + o] = s;
    }
  }
}

extern "C" void kernel_launch(void* const* d_in, const int* in_sizes, int n_in,
                              void* d_out, int out_size, void* d_ws, size_t ws_size,
                              hipStream_t stream) {
  const float* x = (const float*)d_in[0];
  const float* W = (const float*)d_in[1];
  const float* b = (const float*)d_in[2];
  const float* Wf = (const float*)d_in[3];
  const float* bf = (const float*)d_in[4];
  float* out = (float*)d_out;

  const size_t need = (size_t)N_LAYERS * 2 * LCHUNK;          // 28.672 MB (hi only)
  const int nwg = 65536 / TM;                                 // 1024
  if (ws_size >= need) {
    char* whi = (char*)d_ws;
    const int chunks = N_LAYERS * 2 * 7 * 2 * 64;             // 1,792,000
    presplit_kernel<<<(chunks + 255) / 256, 256, 0, stream>>>(W, b, whi);
    (void)hipFuncSetAttribute(reinterpret_cast<const void*>(resnet_main<1>),
                              hipFuncAttributeMaxDynamicSharedMemorySize, SMEM_BYTES);
    resnet_main<1><<<nwg, 128, SMEM_BYTES, stream>>>(x, W, b, Wf, bf, out, whi);
  } else {
    (void)hipFuncSetAttribute(reinterpret_cast<const void*>(resnet_main<0>),
                              hipFuncAttributeMaxDynamicSharedMemorySize, SMEM_BYTES);
    resnet_main<0><<<nwg, 128, SMEM_BYTES, stream>>>(x, W, b, Wf, bf, out, nullptr);
  }
}